// Round 5
// baseline (571.559 us; speedup 1.0000x reference)
//
#include <hip/hip_runtime.h>
#include <hip/hip_bf16.h>

// GPNN_HICO: B=4, N=256, EDGE_F=256, MSG=128, LINK_H=128, ROUNDS=3, CLASSES=600
// Input/output dtype (bf16 vs fp32) detected at runtime (R1/R4 NaN vs R2/R3
// pass proves the detector is required); each kernel branches uniformly on a
// device flag. Internal compute: bf16 MFMA, fp32 accumulate.
// Algebra:
//  - only the valid[b] x valid[b] block matters (valid = human+obj)
//  - m_raw is round-invariant (reference never writes node state back)
//  - e_state_r[b,i,w] = sigmoid(s_{r-1}[b,w,i]) * m_raw[b,w,i]
// 7 dispatches: k_detect, k_prep, k_nf_c, k_r0, k_link2 x2, k_final.

#define B_ 4
#define N_ 256
#define EF_ 256
#define M_ 128
#define CL_ 600
#define ADJ_SZ (B_*N_*N_)

typedef __hip_bfloat16 bf16;
typedef short short8 __attribute__((ext_vector_type(8)));
typedef float f32x4 __attribute__((ext_vector_type(4)));

#define MFMA(a,b,c) __builtin_amdgcn_mfma_f32_16x16x32_bf16(a,b,c,0,0,0)

__device__ __forceinline__ float s2f(short s){
  union { unsigned int u; float f; } x; x.u = ((unsigned int)(unsigned short)s) << 16; return x.f;
}
__device__ __forceinline__ short f2bs(float f){
  bf16 h = __float2bfloat16(f);
  return *reinterpret_cast<short*>(&h);
}
__device__ __forceinline__ float sigm(float x){ return 1.0f/(1.0f+expf(-x)); }
__device__ __forceinline__ float ldx(const void* p, size_t i, bool bf){
  return bf ? s2f(((const short*)p)[i]) : ((const float*)p)[i];
}
__device__ __forceinline__ float dot8(short8 w, const float* x){
  float a = 0.f;
  #pragma unroll
  for (int j=0;j<8;j++) a += x[j]*s2f(w[j]);
  return a;
}

// ---- dtype detector (validated R2/R3): bf16 buffers ~100% sane exponent
// fields; fp32 read as uint16 ~59% (low halves uniform). ----
__global__ __launch_bounds__(64)
void k_detect(const unsigned short* ef, int* flag){
  int t = threadIdx.x;
  int cnt = 0;
  for (int j = 0; j < 64; j++){
    unsigned short u = ef[t*64 + j];
    int e = (u >> 7) & 0xFF;
    cnt += (e >= 96 && e <= 144) ? 1 : 0;
  }
  for (int o = 32; o > 0; o >>= 1) cnt += __shfl_down(cnt, o, 64);
  if (t == 0) *flag = (cnt > 3500) ? 1 : 0;
}

// ---- one kernel for ALL weight repacking (src dtype via flag) ----
// blocks 0..31   : MFMA B-frag packs (pWer 64 units, pWmsgB 32, pWl1 32; 4/block)
// blocks 32..223 : transpose W_ih  (128x384 -> [n*128+k])
// blocks 224..415: transpose W_hh  (128x384)
// blocks 416..715: transpose W_ro  (128x600)
__global__ __launch_bounds__(256)
void k_prep(const void* W_er, const void* W_msg, const void* W_l1,
            const void* W_ih, const void* W_hh, const void* W_ro,
            short* pWer, short* pWmsgB, short* pWl1,
            short* tWih, short* tWhh, short* tWro, const int* dflag)
{
  bool bf = (*dflag != 0);
  int bid = blockIdx.x, t = threadIdx.x;
  if (bid < 32){
    int unit = bid*4 + (t>>6);
    int lane = t & 63;
    const void* src; short* dst; int p; size_t soff = 0;
    if (unit < 64)      { src = W_er;  dst = pWer;   p = unit; }
    else if (unit < 96) { src = W_msg; dst = pWmsgB; p = unit - 64; soff = (size_t)128*M_; }
    else                { src = W_l1;  dst = pWl1;   p = unit - 96; }
    int kk = p >> 3, nt = p & 7;
    int k0 = kk*32 + (lane>>4)*8;
    int n  = nt*16 + (lane&15);
    size_t dbase = ((size_t)p*64 + lane)*8;
    #pragma unroll
    for (int j=0;j<8;j++)
      dst[dbase+j] = f2bs(ldx(src, soff + (size_t)(k0+j)*M_ + n, bf));
  } else if (bid < 224){
    int idx = (bid-32)*256 + t;          // 49152 = 128*384
    int k = idx / 384, n = idx % 384;
    tWih[(size_t)n*M_ + k] = f2bs(ldx(W_ih, idx, bf));
  } else if (bid < 416){
    int idx = (bid-224)*256 + t;
    int k = idx / 384, n = idx % 384;
    tWhh[(size_t)n*M_ + k] = f2bs(ldx(W_hh, idx, bf));
  } else {
    int idx = (bid-416)*256 + t;         // 76800 = 128*600
    int k = idx / 600, n = idx % 600;
    tWro[(size_t)n*M_ + k] = f2bs(ldx(W_ro, idx, bf));
  }
}

// nf[b,v,:] = node @ W_nr + b_nr ; cb[b,v,:] = b_msg + nf @ W_msg[0:128,:]
__global__ __launch_bounds__(128)
void k_nf_c(const void* nodef, const void* W_nr, const void* b_nr,
            const void* W_msg, const void* b_msg, float* nf, float* cb,
            const int* dflag)
{
  bool bf = (*dflag != 0);
  int blk = blockIdx.x; int b = blk >> 8; int v = blk & 255;
  int t = threadIdx.x;  // 128
  __shared__ float xs[EF_];
  __shared__ float nfs[M_];
  size_t xrow = ((size_t)(b*N_)+v)*EF_;
  xs[t]     = ldx(nodef, xrow + t, bf);
  xs[t+128] = ldx(nodef, xrow + t + 128, bf);
  __syncthreads();
  float acc = ldx(b_nr, t, bf);
  for (int k=0;k<EF_;k++) acc += xs[k]*ldx(W_nr, (size_t)k*M_+t, bf);
  nf[((size_t)(b*N_)+v)*M_+t] = acc;
  nfs[t] = acc;
  __syncthreads();
  float acc2 = ldx(b_msg, t, bf);
  for (int k=0;k<M_;k++) acc2 += nfs[k]*ldx(W_msg, (size_t)k*M_+t, bf);
  cb[((size_t)(b*N_)+v)*M_+t] = acc2;
}

// Fused round 0 per (b, i, 32-w tile): MFMA GEMMs.
//   ef = edge @ W_er + b_er
//   mraw = relu(cb[b,w] + ef @ W_msg[128:,:])   (bf16 to ws)
//   s0 = relu(ef @ W_l1 + b_l1) @ W_l2 + b_l2
__global__ __launch_bounds__(256)
void k_r0(const void* edgef, const short* pWer, const void* b_er,
          const short* pWmsgB, const float* cb, const short* pWl1,
          const void* b_l1, const void* W_l2, const void* b_l2,
          const int* hn, const int* on, short* mraw, float* s0,
          const int* dflag)
{
  bool bf = (*dflag != 0);
  int b = blockIdx.z, i = blockIdx.y, w0 = blockIdx.x*32;
  int valid = hn[b] + on[b];
  if (i >= valid || w0 >= valid) return;
  int t = threadIdx.x;
  __shared__ __attribute__((aligned(16))) short EfsB[32][136];
  __shared__ __attribute__((aligned(16))) char uni[32*264*2]; // Xs bf16[32][264] | hls f32[32][132]
  short (*Xs)[264]  = (short(*)[264])uni;
  float (*hls)[132] = (float(*)[132])uni;

  // stage edge rows [32][256] -> bf16 LDS
  {
    int j = t>>3, c = (t&7)*32;
    size_t g = (((size_t)(b*N_)+i)*N_ + (size_t)(w0+j))*EF_ + c;
    if (bf){
      const short8* src = (const short8*)((const short*)edgef + g);
      short8* dst = (short8*)&Xs[j][c];
      #pragma unroll
      for (int u=0;u<4;u++) dst[u] = src[u];
    } else {
      const f32x4* src = (const f32x4*)((const float*)edgef + g);
      #pragma unroll
      for (int u=0;u<8;u++){
        f32x4 v = src[u];
        #pragma unroll
        for (int e=0;e<4;e++) Xs[j][c+u*4+e] = f2bs(v[e]);
      }
    }
  }
  __syncthreads();

  int lane = t & 63, wv = t >> 6;
  int r0 = (wv&1)*16;
  int c0h = wv >> 1;               // column half (0/1), 64 cols each
  int mA = r0 + (lane&15);
  int kq = (lane>>4)*8;
  int qrow = r0 + (lane>>4)*4;

  f32x4 z4 = {0.f,0.f,0.f,0.f};
  f32x4 acc[4] = {z4,z4,z4,z4};
  for (int kk=0;kk<8;kk++){
    short8 a = *(const short8*)&Xs[mA][kk*32 + kq];
    #pragma unroll
    for (int nt=0;nt<4;nt++){
      int gnt = c0h*4 + nt;
      short8 bb = *(const short8*)(pWer + (((size_t)kk*8 + gnt)*64 + lane)*8);
      acc[nt] = MFMA(a, bb, acc[nt]);
    }
  }
  // ef -> LDS bf16 (with bias)
  #pragma unroll
  for (int nt=0;nt<4;nt++){
    int col = c0h*64 + nt*16 + (lane&15);
    float be = ldx(b_er, col, bf);
    #pragma unroll
    for (int r=0;r<4;r++)
      EfsB[qrow+r][col] = f2bs(acc[nt][r] + be);
  }
  __syncthreads();

  // GEMM2 (mraw) + GEMM3 (hl), shared A-frags, K=128
  f32x4 am[4] = {z4,z4,z4,z4};
  f32x4 ah[4] = {z4,z4,z4,z4};
  for (int kk=0;kk<4;kk++){
    short8 a = *(const short8*)&EfsB[mA][kk*32 + kq];
    #pragma unroll
    for (int nt=0;nt<4;nt++){
      int gnt = c0h*4 + nt;
      size_t off = (((size_t)kk*8 + gnt)*64 + lane)*8;
      short8 b1 = *(const short8*)(pWmsgB + off);
      am[nt] = MFMA(a, b1, am[nt]);
      short8 b2 = *(const short8*)(pWl1 + off);
      ah[nt] = MFMA(a, b2, ah[nt]);
    }
  }
  // epilogues
  #pragma unroll
  for (int nt=0;nt<4;nt++){
    int col = c0h*64 + nt*16 + (lane&15);
    float bl = ldx(b_l1, col, bf);
    #pragma unroll
    for (int r=0;r<4;r++){
      int row = qrow + r;
      int w = w0 + row;
      float v = am[nt][r] + cb[((size_t)(b*N_)+w)*M_ + col];
      mraw[(((size_t)(b*N_)+i)*N_ + w)*M_ + col] = f2bs(fmaxf(v, 0.f));
      hls[row][col] = fmaxf(ah[nt][r] + bl, 0.f);
    }
  }
  __syncthreads();
  // s0 GEMV: 8 lanes per row
  {
    int row = t>>3, seg = t&7;
    float p = 0.f;
    #pragma unroll
    for (int k=0;k<16;k++) p += hls[row][seg*16+k] * ldx(W_l2, seg*16+k, bf);
    p += __shfl_down(p, 4, 8);
    p += __shfl_down(p, 2, 8);
    p += __shfl_down(p, 1, 8);
    if (seg==0 && (w0+row) < valid)
      s0[((size_t)(b*N_)+i)*N_ + w0 + row] = p + ldx(b_l2, 0, bf);
  }
}

// link round: s_next[b,i,w] = relu(sig(s_prev[b,w,i])*mraw[b,w,i,:] @ W_l1 + b_l1) @ W_l2 + b_l2
__global__ __launch_bounds__(256)
void k_link2(const short* mraw, const float* s_prev, const short* pWl1,
             const void* b_l1, const void* W_l2, const void* b_l2,
             const int* hn, const int* on, float* s_next, const int* dflag)
{
  bool bf = (*dflag != 0);
  int b = blockIdx.z, i = blockIdx.y, w0 = blockIdx.x*32;
  int valid = hn[b] + on[b];
  if (i >= valid || w0 >= valid) return;
  int t = threadIdx.x;
  __shared__ __attribute__((aligned(16))) short EsB[32][136];
  __shared__ __attribute__((aligned(16))) float hls[32][132];
  __shared__ float sg[32];
  if (t < 32){
    int w = w0 + t;
    sg[t] = (w < valid) ? sigm(s_prev[((size_t)(b*N_)+w)*N_ + i]) : 0.f;
  }
  __syncthreads();
  {
    int j = t>>3, c = (t&7)*16;
    const short* src = mraw + (((size_t)(b*N_)+(size_t)(w0+j))*N_ + i)*M_;
    float s = sg[j];
    #pragma unroll
    for (int u=0;u<2;u++){
      short8 v = *(const short8*)(src + c + u*8);
      short8 o;
      #pragma unroll
      for (int e=0;e<8;e++) o[e] = f2bs(s2f(v[e])*s);
      *(short8*)&EsB[j][c+u*8] = o;
    }
  }
  __syncthreads();

  int lane = t & 63, wv = t >> 6;
  int r0 = (wv&1)*16;
  int c0h = wv >> 1;
  int mA = r0 + (lane&15);
  int kq = (lane>>4)*8;
  int qrow = r0 + (lane>>4)*4;

  f32x4 z4 = {0.f,0.f,0.f,0.f};
  f32x4 ah[4] = {z4,z4,z4,z4};
  for (int kk=0;kk<4;kk++){
    short8 a = *(const short8*)&EsB[mA][kk*32 + kq];
    #pragma unroll
    for (int nt=0;nt<4;nt++){
      int gnt = c0h*4 + nt;
      short8 b2 = *(const short8*)(pWl1 + (((size_t)kk*8 + gnt)*64 + lane)*8);
      ah[nt] = MFMA(a, b2, ah[nt]);
    }
  }
  #pragma unroll
  for (int nt=0;nt<4;nt++){
    int col = c0h*64 + nt*16 + (lane&15);
    float bl = ldx(b_l1, col, bf);
    #pragma unroll
    for (int r=0;r<4;r++)
      hls[qrow+r][col] = fmaxf(ah[nt][r] + bl, 0.f);
  }
  __syncthreads();
  {
    int row = t>>3, seg = t&7;
    float p = 0.f;
    #pragma unroll
    for (int k=0;k<16;k++) p += hls[row][seg*16+k] * ldx(W_l2, seg*16+k, bf);
    p += __shfl_down(p, 4, 8);
    p += __shfl_down(p, 2, 8);
    p += __shfl_down(p, 1, 8);
    if (seg==0 && (w0+row) < valid)
      s_next[((size_t)(b*N_)+i)*N_ + w0 + row] = p + ldx(b_l2, 0, bf);
  }
}

// final: pred_adj (incl. zero padding) ; m_sum = sum_w sig(s2)*mraw ; GRU ; readout.
// Grid covers ALL i so the whole output is written every call.
__global__ __launch_bounds__(128)
void k_final(const short* mraw, const float* s2, const float* nf,
             const short* tWih, const void* b_ih,
             const short* tWhh, const void* b_hh,
             const short* tWro, const void* b_ro,
             const int* hn, const int* on, void* out, const int* dflag)
{
  bool bf = (*dflag != 0);
  int i = blockIdx.x, b = blockIdx.y;
  int valid = hn[b] + on[b];
  int t = threadIdx.x;  // 128
  size_t adj = ((size_t)(b*N_)+i)*N_;
  size_t lab = (size_t)ADJ_SZ + ((size_t)(b*N_)+i)*CL_;
  short* o16 = (short*)out;
  float* o32 = (float*)out;
  if (i >= valid){
    if (bf){
      for (int w=t; w<N_; w+=128) o16[adj+w] = 0;
      for (int c=t; c<CL_; c+=128) o16[lab+c] = 0;
    } else {
      for (int w=t; w<N_; w+=128) o32[adj+w] = 0.f;
      for (int c=t; c<CL_; c+=128) o32[lab+c] = 0.f;
    }
    return;
  }
  __shared__ float sgs[N_];
  __shared__ float xsh[M_], hsh[M_], hns[M_];
  const float* srow = s2 + ((size_t)(b*N_)+i)*N_;
  for (int w=t; w<N_; w+=128){
    float v = 0.f; float sv = 0.f;
    if (w < valid){ v = srow[w]; sv = sigm(v); }
    if (bf) o16[adj+w] = (w < valid) ? f2bs(v) : (short)0;
    else    o32[adj+w] = (w < valid) ? v : 0.f;
    sgs[w] = sv;
  }
  __syncthreads();
  const short* mrow = mraw + (((size_t)(b*N_)+i)*N_)*M_;
  float acc = 0.f;
  for (int w=0; w<valid; w++) acc += sgs[w]*s2f(mrow[(size_t)w*M_ + t]);
  xsh[t] = acc;
  hsh[t] = nf[((size_t)(b*N_)+i)*M_ + t];
  __syncthreads();
  float gi[3], gh[3];
  #pragma unroll
  for (int g=0; g<3; g++){
    int o = g*M_ + t;
    float a = ldx(b_ih, o, bf), c = ldx(b_hh, o, bf);
    const short8* wi = (const short8*)(tWih + (size_t)o*M_);
    const short8* wh = (const short8*)(tWhh + (size_t)o*M_);
    #pragma unroll 4
    for (int k8=0;k8<16;k8++){
      a += dot8(wi[k8], &xsh[k8*8]);
      c += dot8(wh[k8], &hsh[k8*8]);
    }
    gi[g] = a; gh[g] = c;
  }
  float r  = sigm(gi[0] + gh[0]);
  float z  = sigm(gi[1] + gh[1]);
  float nn = tanhf(gi[2] + r*gh[2]);
  float hnew = (1.f - z)*nn + z*hsh[t];
  hns[t] = hnew;
  __syncthreads();
  for (int cls=t; cls<CL_; cls+=128){
    float a = ldx(b_ro, cls, bf);
    const short8* wr = (const short8*)(tWro + (size_t)cls*M_);
    #pragma unroll 4
    for (int k8=0;k8<16;k8++) a += dot8(wr[k8], &hns[k8*8]);
    if (bf) o16[lab+cls] = f2bs(a);
    else    o32[lab+cls] = a;
  }
}

extern "C" void kernel_launch(void* const* d_in, const int* in_sizes, int n_in,
                              void* d_out, int out_size, void* d_ws, size_t ws_size,
                              hipStream_t stream)
{
  const void* edgef = d_in[0];
  const void* nodef = d_in[1];
  const int*  hn    = (const int*)d_in[4];
  const int*  on    = (const int*)d_in[5];
  const void* W_er  = d_in[6];  const void* b_er  = d_in[7];
  const void* W_nr  = d_in[8];  const void* b_nr  = d_in[9];
  const void* W_l1  = d_in[10]; const void* b_l1  = d_in[11];
  const void* W_l2  = d_in[12]; const void* b_l2  = d_in[13];
  const void* W_msg = d_in[14]; const void* b_msg = d_in[15];
  const void* W_ih  = d_in[16]; const void* b_ih  = d_in[17];
  const void* W_hh  = d_in[18]; const void* b_hh  = d_in[19];
  const void* W_ro  = d_in[20]; const void* b_ro  = d_in[21];

  char*  ws     = (char*)d_ws;
  short* mraw   = (short*)(ws);                 // 67,108,864 B
  float* s_a    = (float*)(ws + 67108864);      //  1,048,576 B
  float* s_b    = (float*)(ws + 68157440);      //  1,048,576 B
  float* nf     = (float*)(ws + 69206016);      //    524,288 B
  float* cb     = (float*)(ws + 69730304);      //    524,288 B
  short* pWer   = (short*)(ws + 70254592);      //     65,536 B
  short* pWmsgB = (short*)(ws + 70320128);      //     32,768 B
  short* pWl1   = (short*)(ws + 70352896);      //     32,768 B
  short* tWih   = (short*)(ws + 70385664);      //     98,304 B
  short* tWhh   = (short*)(ws + 70483968);      //     98,304 B
  short* tWro   = (short*)(ws + 70582272);      //    153,600 B
  int*   dflag  = (int*)  (ws + 70834176);      //          4 B

  k_detect<<<1, 64, 0, stream>>>((const unsigned short*)edgef, dflag);
  k_prep<<<716, 256, 0, stream>>>(W_er, W_msg, W_l1, W_ih, W_hh, W_ro,
                                  pWer, pWmsgB, pWl1, tWih, tWhh, tWro, dflag);
  k_nf_c<<<B_*N_, 128, 0, stream>>>(nodef, W_nr, b_nr, W_msg, b_msg, nf, cb, dflag);
  dim3 g2(N_/32, N_, B_);
  k_r0<<<g2, 256, 0, stream>>>(edgef, pWer, b_er, pWmsgB, cb, pWl1,
                               b_l1, W_l2, b_l2, hn, on, mraw, s_a, dflag);
  k_link2<<<g2, 256, 0, stream>>>(mraw, s_a, pWl1, b_l1, W_l2, b_l2, hn, on, s_b, dflag);
  k_link2<<<g2, 256, 0, stream>>>(mraw, s_b, pWl1, b_l1, W_l2, b_l2, hn, on, s_a, dflag);
  k_final<<<dim3(N_, B_), 128, 0, stream>>>(mraw, s_a, nf, tWih, b_ih, tWhh, b_hh,
                                            tWro, b_ro, hn, on, d_out, dflag);
}